// Round 24
// baseline (540.951 us; speedup 1.0000x reference)
//
#include <hip/hip_runtime.h>
#include <cstdint>
#include <cstddef>
#include <math.h>

#define T_SEQ  1024
#define DMODEL 1024
#define NHEAD  16
#define HDIM   64
#define NEXP   8
#define IDIM   4096
#define NTOK   2048
#define NSLOT  4096

typedef short bf16x8 __attribute__((ext_vector_type(8)));
typedef short s16x4  __attribute__((ext_vector_type(4)));
typedef float floatx4 __attribute__((ext_vector_type(4)));
typedef unsigned int uintx4 __attribute__((ext_vector_type(4)));

__device__ __forceinline__ float bf2f(short s) {
  return __uint_as_float(((unsigned)(unsigned short)s) << 16);
}
__device__ __forceinline__ short f2bf(float f) {
  unsigned u = __float_as_uint(f);
  unsigned r = (u + 0x7FFFu + ((u >> 16) & 1u)) >> 16;
  return (short)r;
}
// hardware packed fp32->bf16 (RNE), 2 elems / instr; low16 = cvt(arg0)
__device__ __forceinline__ unsigned cvt_pk_bf16(float lo, float hi) {
  unsigned r;
  asm("v_cvt_pk_bf16_f32 %0, %1, %2" : "=v"(r) : "v"(lo), "v"(hi));
  return r;
}
__device__ __forceinline__ uintx4 pack8_bf16(floatx4 a, floatx4 b) {
  uintx4 u;
  u[0] = cvt_pk_bf16(a[0], a[1]);
  u[1] = cvt_pk_bf16(a[2], a[3]);
  u[2] = cvt_pk_bf16(b[0], b[1]);
  u[3] = cvt_pk_bf16(b[2], b[3]);
  return u;
}
// split 8 fp32 into hi-bf16 + lo-bf16 (lo = x - hi, RNE both)
__device__ __forceinline__ void split8(const float* x, uintx4& hi, uintx4& lo) {
  #pragma unroll
  for (int i = 0; i < 4; i++) {
    unsigned h = cvt_pk_bf16(x[2*i], x[2*i+1]);
    hi[i] = h;
    float r0 = x[2*i]   - __uint_as_float(h << 16);
    float r1 = x[2*i+1] - __uint_as_float(h & 0xffff0000u);
    lo[i] = cvt_pk_bf16(r0, r1);
  }
}
// async global->LDS DMA, 16B per lane. LDS dest = wave-uniform base + lane*16.
__device__ __forceinline__ void async_load16(const short* g, short* l) {
  __builtin_amdgcn_global_load_lds(
      (const __attribute__((address_space(1))) void*)g,
      (__attribute__((address_space(3))) void*)l, 16, 0, 0);
}

// ---------------- RMSNorm: fp32 in -> fp32 out ----------------
__global__ __launch_bounds__(256) void rmsnorm_f32_kernel(
    const float* __restrict__ x, const float* __restrict__ w, float* __restrict__ out) {
  int row = blockIdx.x, tid = threadIdx.x;
  const floatx4* xr = (const floatx4*)(x + (size_t)row * DMODEL);
  floatx4 v = xr[tid];
  float ss = v[0]*v[0] + v[1]*v[1] + v[2]*v[2] + v[3]*v[3];
  #pragma unroll
  for (int off = 32; off > 0; off >>= 1) ss += __shfl_xor(ss, off);
  __shared__ float wsum[4];
  int wid = tid >> 6;
  if ((tid & 63) == 0) wsum[wid] = ss;
  __syncthreads();
  float tot = wsum[0] + wsum[1] + wsum[2] + wsum[3];
  float r = rsqrtf(tot * (1.0f / DMODEL) + 1e-6f);
  floatx4 wv = ((const floatx4*)w)[tid];
  floatx4 o;
  o[0] = v[0]*r*wv[0]; o[1] = v[1]*r*wv[1];
  o[2] = v[2]*r*wv[2]; o[3] = v[3]*r*wv[3];
  ((floatx4*)(out + (size_t)row * DMODEL))[tid] = o;
}

// ---------------- RMSNorm: fp32 in -> bf16 out (for MoE input) ----------------
__global__ __launch_bounds__(256) void rmsnorm_bf16_kernel(
    const float* __restrict__ x, const float* __restrict__ w, short* __restrict__ out) {
  int row = blockIdx.x, tid = threadIdx.x;
  const floatx4* xr = (const floatx4*)(x + (size_t)row * DMODEL);
  floatx4 v = xr[tid];
  float ss = v[0]*v[0] + v[1]*v[1] + v[2]*v[2] + v[3]*v[3];
  #pragma unroll
  for (int off = 32; off > 0; off >>= 1) ss += __shfl_xor(ss, off);
  __shared__ float wsum[4];
  int wid = tid >> 6;
  if ((tid & 63) == 0) wsum[wid] = ss;
  __syncthreads();
  float tot = wsum[0] + wsum[1] + wsum[2] + wsum[3];
  float r = rsqrtf(tot * (1.0f / DMODEL) + 1e-6f);
  floatx4 wv = ((const floatx4*)w)[tid];
  s16x4 o;
  o[0] = f2bf(v[0]*r*wv[0]); o[1] = f2bf(v[1]*r*wv[1]);
  o[2] = f2bf(v[2]*r*wv[2]); o[3] = f2bf(v[3]*r*wv[3]);
  *(s16x4*)(out + (size_t)row * DMODEL + tid*4) = o;
}

// ---------------- split-bf16 MFMA GEMM, double-buffered LDS (R17-validated dbuf) ----------------
// C = A@W^T + bias [+resid]. Issue next-tile loads -> MFMA cur -> split+write nxt
// (disjoint buffer) -> single barrier per K-step.
template<int RESID>
__global__ __launch_bounds__(256) void gemm_3bf16(
    const float* __restrict__ A, const float* __restrict__ W,
    const float* __restrict__ bias, const float* __restrict__ resid,
    float* __restrict__ C, int N, int K) {
  __shared__ __attribute__((aligned(16))) short Ahi[2][64*40];
  __shared__ __attribute__((aligned(16))) short Alo[2][64*40];
  __shared__ __attribute__((aligned(16))) short Whi[2][64*40];
  __shared__ __attribute__((aligned(16))) short Wlo[2][64*40];
  int tid = threadIdx.x, lane = tid & 63, wid = tid >> 6;
  int wm = wid >> 1, wn = wid & 1;
  int m0 = blockIdx.y * 64, n0 = blockIdx.x * 64;
  floatx4 zero4 = {0.f,0.f,0.f,0.f};
  floatx4 acc[2][2];
  #pragma unroll
  for (int mi = 0; mi < 2; mi++)
    #pragma unroll
    for (int nj = 0; nj < 2; nj++) acc[mi][nj] = zero4;

  int ar = tid >> 2, ak = (tid & 3) * 8;
  const float* Ap = A + (size_t)(m0 + ar) * K + ak;
  const float* Wp = W + (size_t)(n0 + ar) * K + ak;
  int rsel = lane & 15, kseg = (lane >> 4) * 8;

  // prologue: stage tile 0 into buffer 0
  {
    float abuf[8], wbuf[8];
    *(floatx4*)(abuf)     = *(const floatx4*)(Ap);
    *(floatx4*)(abuf + 4) = *(const floatx4*)(Ap + 4);
    *(floatx4*)(wbuf)     = *(const floatx4*)(Wp);
    *(floatx4*)(wbuf + 4) = *(const floatx4*)(Wp + 4);
    uintx4 ahi, alo, whi, wlo;
    split8(abuf, ahi, alo);
    split8(wbuf, whi, wlo);
    *(uintx4*)(&Ahi[0][ar*40 + ak]) = ahi;
    *(uintx4*)(&Alo[0][ar*40 + ak]) = alo;
    *(uintx4*)(&Whi[0][ar*40 + ak]) = whi;
    *(uintx4*)(&Wlo[0][ar*40 + ak]) = wlo;
  }
  __syncthreads();

  for (int kk = 0; kk < K; kk += 32) {
    int cur = (kk >> 5) & 1;
    int nxt = cur ^ 1;
    bool more = (kk + 32 < K);
    // issue next-tile global loads (latency hides under MFMAs)
    float nab[8], nwb[8];
    if (more) {
      *(floatx4*)(nab)     = *(const floatx4*)(Ap + kk + 32);
      *(floatx4*)(nab + 4) = *(const floatx4*)(Ap + kk + 36);
      *(floatx4*)(nwb)     = *(const floatx4*)(Wp + kk + 32);
      *(floatx4*)(nwb + 4) = *(const floatx4*)(Wp + kk + 36);
    }
    // read cur fragments + MFMA
    bf16x8 afh[2], afl[2], wfh[2], wfl[2];
    #pragma unroll
    for (int mi = 0; mi < 2; mi++) {
      int row = (wm*32 + mi*16 + rsel)*40 + kseg;
      afh[mi] = *(const bf16x8*)(&Ahi[cur][row]);
      afl[mi] = *(const bf16x8*)(&Alo[cur][row]);
    }
    #pragma unroll
    for (int nj = 0; nj < 2; nj++) {
      int row = (wn*32 + nj*16 + rsel)*40 + kseg;
      wfh[nj] = *(const bf16x8*)(&Whi[cur][row]);
      wfl[nj] = *(const bf16x8*)(&Wlo[cur][row]);
    }
    #pragma unroll
    for (int mi = 0; mi < 2; mi++)
      #pragma unroll
      for (int nj = 0; nj < 2; nj++) {
        acc[mi][nj] = __builtin_amdgcn_mfma_f32_16x16x32_bf16(afl[mi], wfh[nj], acc[mi][nj], 0, 0, 0);
        acc[mi][nj] = __builtin_amdgcn_mfma_f32_16x16x32_bf16(afh[mi], wfl[nj], acc[mi][nj], 0, 0, 0);
        acc[mi][nj] = __builtin_amdgcn_mfma_f32_16x16x32_bf16(afh[mi], wfh[nj], acc[mi][nj], 0, 0, 0);
      }
    // split + write next buffer (disjoint from cur)
    if (more) {
      uintx4 ahi, alo, whi, wlo;
      split8(nab, ahi, alo);
      split8(nwb, whi, wlo);
      *(uintx4*)(&Ahi[nxt][ar*40 + ak]) = ahi;
      *(uintx4*)(&Alo[nxt][ar*40 + ak]) = alo;
      *(uintx4*)(&Whi[nxt][ar*40 + ak]) = whi;
      *(uintx4*)(&Wlo[nxt][ar*40 + ak]) = wlo;
    }
    __syncthreads();
  }
  int rj = (lane >> 4) * 4, cn = lane & 15;
  #pragma unroll
  for (int mi = 0; mi < 2; mi++) {
    #pragma unroll
    for (int nj = 0; nj < 2; nj++) {
      int n = n0 + wn*32 + nj*16 + cn;
      float bn = bias[n];
      #pragma unroll
      for (int j = 0; j < 4; j++) {
        int m = m0 + wm*32 + mi*16 + rj + j;
        float v = acc[mi][nj][j] + bn;
        if (RESID) v += resid[(size_t)m * N + n];
        C[(size_t)m * N + n] = v;
      }
    }
  }
}

// ---------------- RoPE table (fp64 generation) ----------------
__global__ void rope_table_kernel(float* __restrict__ cost, float* __restrict__ sint) {
  int t = blockIdx.x, d = threadIdx.x;  // block 32
  double theta = pow(10000.0, -(double)d / 32.0);
  double f = (double)t * theta;
  cost[t*32 + d] = (float)cos(f);
  sint[t*32 + d] = (float)sin(f);
}

// ---------------- RoPE + transpose q,k to [B][H][T][hd], fp32 ----------------
__global__ __launch_bounds__(256) void rope_kernel(
    const float* __restrict__ qkv, const float* __restrict__ cost, const float* __restrict__ sint,
    float* __restrict__ qr, float* __restrict__ kr) {
  int wid = threadIdx.x >> 6, lane = threadIdx.x & 63;
  int idx = blockIdx.x * 4 + wid;        // over NTOK*NHEAD
  int h = idx & 15, n = idx >> 4;
  int t = n & (T_SEQ - 1), b = n >> 10;
  const float* base = qkv + (size_t)n * 3072 + h * 192;
  int d2 = lane & 31;
  float c = cost[t*32 + d2], s = sint[t*32 + d2];
  float q1 = base[d2],      q2 = base[d2 + 32];
  float k1 = base[64 + d2], k2 = base[96 + d2];
  float qo = (lane < 32) ? (q1*c - q2*s) : (q1*s + q2*c);
  float ko = (lane < 32) ? (k1*c - k2*s) : (k1*s + k2*c);
  size_t orow = ((size_t)(b*NHEAD + h) * T_SEQ + t) * HDIM;
  qr[orow + lane] = qo;
  kr[orow + lane] = ko;
}

// ---------------- V transpose: qkvf -> vrT[bh][d][t]  (for MFMA B-operand) ----------------
__global__ __launch_bounds__(256) void vtrans_kernel(
    const float* __restrict__ qkvf, float* __restrict__ vrT) {
  __shared__ __attribute__((aligned(16))) float tile[64][68];
  int bh = blockIdx.x, t0 = blockIdx.y * 64;
  int b = bh >> 4, h = bh & 15;
  int tid = threadIdx.x;
  int r = tid >> 2, seg = (tid & 3) * 16;
  const float* src = qkvf + ((size_t)(b*T_SEQ + t0 + r))*3072 + h*192 + 128 + seg;
  floatx4 v0 = *(const floatx4*)(src);
  floatx4 v1 = *(const floatx4*)(src + 4);
  floatx4 v2 = *(const floatx4*)(src + 8);
  floatx4 v3 = *(const floatx4*)(src + 12);
  *(floatx4*)(&tile[r][seg])      = v0;
  *(floatx4*)(&tile[r][seg + 4])  = v1;
  *(floatx4*)(&tile[r][seg + 8])  = v2;
  *(floatx4*)(&tile[r][seg + 12]) = v3;
  __syncthreads();
  int dr = r, tseg = seg;
  floatx4 o0, o1, o2, o3;
  #pragma unroll
  for (int i = 0; i < 4; i++) {
    o0[i] = tile[tseg + i][dr];
    o1[i] = tile[tseg + 4 + i][dr];
    o2[i] = tile[tseg + 8 + i][dr];
    o3[i] = tile[tseg + 12 + i][dr];
  }
  float* dst = vrT + ((size_t)(bh*HDIM + dr))*T_SEQ + t0 + tseg;
  *(floatx4*)(dst)      = o0;
  *(floatx4*)(dst + 4)  = o1;
  *(floatx4*)(dst + 8)  = o2;
  *(floatx4*)(dst + 12) = o3;
}

// ---------------- MFMA flash attention, split-bf16 (3-term), fp32-class accuracy ----------------
__global__ __launch_bounds__(256) void attn_mfma_kernel(
    const float* __restrict__ qr_, const float* __restrict__ kr_,
    const float* __restrict__ vrT_, float* __restrict__ attno) {
  __shared__ __attribute__((aligned(16))) short Qhi[64*72];
  __shared__ __attribute__((aligned(16))) short Qlo[64*72];
  __shared__ __attribute__((aligned(16))) short Khi[64*72];
  __shared__ __attribute__((aligned(16))) short Klo[64*72];
  __shared__ __attribute__((aligned(16))) short Vhi[64*72];
  __shared__ __attribute__((aligned(16))) short Vlo[64*72];
  __shared__ __attribute__((aligned(16))) unsigned Pp[64*68];
  int tid = threadIdx.x, lane = tid & 63, w = tid >> 6;
  int bh = blockIdx.x;
  int qt = 15 - (int)blockIdx.y;          // heavy tiles first
  int q0 = qt * 64;
  int b = bh >> 4, h = bh & 15;
  const float* Qb  = qr_  + ((size_t)bh * T_SEQ + q0) * HDIM;
  const float* Kb  = kr_  + (size_t)bh * T_SEQ * HDIM;
  const float* Vtb = vrT_ + (size_t)bh * HDIM * T_SEQ;

  int srow = tid >> 2, sseg = (tid & 3) * 16;
  // stage Q once (split)
  {
    const float* src = Qb + srow*HDIM + sseg;
    float b0[8], b1[8];
    *(floatx4*)(b0)   = *(const floatx4*)(src);
    *(floatx4*)(b0+4) = *(const floatx4*)(src + 4);
    *(floatx4*)(b1)   = *(const floatx4*)(src + 8);
    *(floatx4*)(b1+4) = *(const floatx4*)(src + 12);
    uintx4 h0, l0, h1, l1;
    split8(b0, h0, l0); split8(b1, h1, l1);
    *(uintx4*)(&Qhi[srow*72 + sseg])     = h0;
    *(uintx4*)(&Qhi[srow*72 + sseg + 8]) = h1;
    *(uintx4*)(&Qlo[srow*72 + sseg])     = l0;
    *(uintx4*)(&Qlo[srow*72 + sseg + 8]) = l1;
  }

  int rsel = lane & 15, kseg = (lane >> 4) * 8, cl = lane & 15;
  int rbase = w*16 + (lane >> 4) * 4;   // +j = local q row (C layout)
  const float scale = 0.03125f;          // (D=1024)^-0.5 per reference
  float mrow[4] = {-1e30f,-1e30f,-1e30f,-1e30f};
  float lrow[4] = {0.f,0.f,0.f,0.f};
  floatx4 zero4 = {0.f,0.f,0.f,0.f};
  floatx4 Of[4];
  #pragma unroll
  for (int f = 0; f < 4; f++) Of[f] = zero4;

  int ntiles = qt + 1;
  for (int kt = 0; kt < ntiles; kt++) {
    int kbase = kt << 6;
    const float* kp = Kb  + (size_t)(kbase + srow)*HDIM + sseg;
    const float* vp = Vtb + (size_t)srow*T_SEQ + kbase + sseg;
    float kb0[8], kb1[8], vb0[8], vb1[8];
    *(floatx4*)(kb0)   = *(const floatx4*)(kp);
    *(floatx4*)(kb0+4) = *(const floatx4*)(kp + 4);
    *(floatx4*)(kb1)   = *(const floatx4*)(kp + 8);
    *(floatx4*)(kb1+4) = *(const floatx4*)(kp + 12);
    *(floatx4*)(vb0)   = *(const floatx4*)(vp);
    *(floatx4*)(vb0+4) = *(const floatx4*)(vp + 4);
    *(floatx4*)(vb1)   = *(const floatx4*)(vp + 8);
    *(floatx4*)(vb1+4) = *(const floatx4*)(vp + 12);
    __syncthreads();   // previous tile's reads complete
    {
      uintx4 h0, l0, h1, l1;
      split8(kb0, h0, l0); split8(kb1, h1, l1);
      *(uintx4*)(&Khi[srow*72 + sseg])     = h0;
      *(uintx4*)(&Khi[srow*72 + sseg + 8]) = h1;
      *(uintx4*)(&Klo[srow*72 + sseg])     = l0;
      *(uintx4*)(&Klo[srow*72 + sseg + 8]) = l1;
      split8(vb0, h0, l0); split8(vb1, h1, l1);
      *(uintx4*)(&Vhi[srow*72 + sseg])     = h0;
      *(uintx4*)(&Vhi[srow*72 + sseg + 8]) = h1;
      *(uintx4*)(&Vlo[srow*72 + sseg])     = l0;
      *(uintx4*)(&Vlo[srow*72 + sseg + 8]) = l1;
    }
    __syncthreads();
    // ---- QK^T: S frags (rows w*16.., cols f*16+cl) ----
    floatx4 sf[4];
    #pragma unroll
    for (int f = 0; f < 4; f++) sf[f] = zero4;
    #pragma unroll
    for (int c = 0; c < 2; c++) {
      int ko = c*32 + kseg;
      bf16x8 qh = *(const bf16x8*)(&Qhi[(w*16 + rsel)*72 + ko]);
      bf16x8 ql = *(const bf16x8*)(&Qlo[(w*16 + rsel)*72 + ko]);
      #pragma unroll
      for (int f = 0; f < 4; f++) {
        bf16x8 kh = *(const bf16x8*)(&Khi[(f*16 + rsel)*72 + ko]);
        bf16x8 kl = *(const bf16x8*)(&Klo[(f*16 + rsel)*72 + ko]);
        sf[f] = __builtin_amdgcn_mfma_f32_16x16x32_bf16(ql, kh, sf[f], 0, 0, 0);
        sf[f] = __builtin_amdgcn_mfma_f32_16x16x32_bf16(qh, kl, sf[f], 0, 0, 0);
        sf[f] = __builtin_amdgcn_mfma_f32_16x16x32_bf16(qh, kh, sf[f], 0, 0, 0);
      }
    }
    // ---- causal mask + scale + row max ----
    float pm[4] = {-1e30f,-1e30f,-1e30f,-1e30f};
    #pragma unroll
    for (int f = 0; f < 4; f++) {
      int col = kbase + f*16 + cl;
      #pragma unroll
      for (int j = 0; j < 4; j++) {
        float s = sf[f][j];
        s = (col <= q0 + rbase + j) ? s*scale : -1e30f;
        sf[f][j] = s;
        pm[j] = fmaxf(pm[j], s);
      }
    }
    #pragma unroll
    for (int off = 1; off < 16; off <<= 1)
      #pragma unroll
      for (int j = 0; j < 4; j++) pm[j] = fmaxf(pm[j], __shfl_xor(pm[j], off));
    // ---- online softmax ----
    float sc[4], rs[4] = {0.f,0.f,0.f,0.f};
    #pragma unroll
    for (int j = 0; j < 4; j++) {
      float mn = fmaxf(mrow[j], pm[j]);
      sc[j] = __expf(mrow[j] - mn);
      mrow[j] = mn;
    }
    #pragma unroll
    for (int f = 0; f < 4; f++) {
      #pragma unroll
      for (int j = 0; j < 4; j++) {
        float p = (sf[f][j] > -1e29f) ? __expf(sf[f][j] - mrow[j]) : 0.f;
        rs[j] += p;
        unsigned hp = cvt_pk_bf16(p, 0.f);
        float ph = __uint_as_float(hp << 16);
        unsigned lp = cvt_pk_bf16(p - ph, 0.f);
        Pp[(rbase + j)*68 + f*16 + cl] = (hp << 16) | (lp & 0xffffu);
      }
    }
    #pragma unroll
    for (int off = 1; off < 16; off <<= 1)
      #pragma unroll
      for (int j = 0; j < 4; j++) rs[j] += __shfl_xor(rs[j], off);
    #pragma unroll
    for (int j = 0; j < 4; j++) lrow[j] = lrow[j]*sc[j] + rs[j];
    #pragma unroll
    for (int f = 0; f < 4; f++)
      #pragma unroll
      for (int j = 0; j < 4; j++) Of[f][j] *= sc[j];
    __syncthreads();   // P visible (ordering safety)
    // ---- PV: O += P * V^T^T  (A=P rows q, B=VT rows d) ----
    #pragma unroll
    for (int c = 0; c < 2; c++) {
      int prow = (w*16 + rsel)*68 + c*32 + kseg;
      uintx4 d0 = *(const uintx4*)(&Pp[prow]);
      uintx4 d1 = *(const uintx4*)(&Pp[prow + 4]);
      uintx4 phw, plw;
      phw[0] = (d0[0] >> 16) | (d0[1] & 0xffff0000u);
      phw[1] = (d0[2] >> 16) | (d0[3] & 0xffff0000u);
      phw[2] = (d1[0] >> 16) | (d1[1] & 0xffff0000u);
      phw[3] = (d1[2] >> 16) | (d1[3] & 0xffff0000u);
      plw[0] = (d0[0] & 0xffffu) | (d0[1] << 16);
      plw[1] = (d0[2] & 0xffffu) | (d0[3] << 16);
      plw[2] = (d1[0] & 0xffffu) | (d1[1] << 16);
      plw[3] = (d1[2] & 0xffffu) | (d1[3] << 16);
      bf16x8 Ph = *(bf16x8*)&phw;
      bf16x8 Pl = *(bf16x8*)&plw;
      int ko = c*32 + kseg;
      #pragma unroll
      for (int f = 0; f < 4; f++) {
        bf16x8 vh = *(const bf16x8*)(&Vhi[(f*16 + rsel)*72 + ko]);
        bf16x8 vl = *(const bf16x8*)(&Vlo[(f*16 + rsel)*72 + ko]);
        Of[f] = __builtin_amdgcn_mfma_f32_16x16x32_bf16(Pl, vh, Of[f], 0, 0, 0);
        Of[f] = __builtin_amdgcn_mfma_f32_16x16x32_bf16(Ph, vl, Of[f], 0, 0, 0);
        Of[f] = __builtin_amdgcn_mfma_f32_16x16x32_bf16(Ph, vh, Of[f], 0, 0, 0);
      }
    }
  }
  // ---- epilogue ----
  #pragma unroll
  for (int j = 0; j < 4; j++) {
    float inv = 1.0f / lrow[j];
    size_t rowoff = ((size_t)(b*T_SEQ + q0 + rbase + j))*DMODEL + h*HDIM;
    #pragma unroll
    for (int f = 0; f < 4; f++)
      attno[rowoff + f*16 + cl] = Of[f][j] * inv;
  }
}

// ---------------- gate: FULL FP64 path (inline rmsnorm of fp32-accurate h1) ----------------
__global__ __launch_bounds__(64) void gate_kernel(
    const float* __restrict__ h1, const float* __restrict__ lnw, const float* __restrict__ gw,
    float* __restrict__ probs, int* __restrict__ pair, float* __restrict__ gpair,
    int* __restrict__ counts) {
  int n = blockIdx.x, lane = threadIdx.x;
  const float* xp = h1 + (size_t)n * DMODEL + lane*16;
  float xv[16];
  double ss = 0.0;
  #pragma unroll
  for (int j = 0; j < 16; j++) { xv[j] = xp[j]; ss += (double)xv[j] * (double)xv[j]; }
  #pragma unroll
  for (int off = 32; off > 0; off >>= 1) ss += __shfl_xor(ss, off);
  double r = 1.0 / sqrt(ss * (1.0 / DMODEL) + 1e-6);
  const float* wp = lnw + lane*16;
  double xf[16];
  #pragma unroll
  for (int j = 0; j < 16; j++) xf[j] = (double)xv[j] * r * (double)wp[j];
  double logit[8];
  #pragma unroll
  for (int e = 0; e < 8; e++) {
    const float* g = gw + e*DMODEL + lane*16;
    double acc = 0.0;
    #pragma unroll
    for (int j = 0; j < 16; j++) acc += xf[j] * (double)g[j];
    logit[e] = acc;
  }
  #pragma unroll
  for (int e = 0; e < 8; e++)
    #pragma unroll
    for (int off = 32; off > 0; off >>= 1) logit[e] += __shfl_xor(logit[e], off);
  double mxl = logit[0];
  #pragma unroll
  for (int e = 1; e < 8; e++) mxl = fmax(mxl, logit[e]);
  double p[8], Z = 0.0;
  #pragma unroll
  for (int e = 0; e < 8; e++) { p[e] = exp(logit[e] - mxl); Z += p[e]; }
  double invZ = 1.0 / Z;
  #pragma unroll
  for (int e = 0; e < 8; e++) p[e] *= invZ;
  int e0 = 0; double b0 = p[0];
  #pragma unroll
  for (int e = 1; e < 8; e++) if (p[e] > b0) { b0 = p[e]; e0 = e; }
  int e1 = -1; double b1 = -1.0;
  #pragma unroll
  for (int e = 0; e < 8; e++) if (e != e0 && p[e] > b1) { b1 = p[e]; e1 = e; }
  if (lane == 0) {
    #pragma unroll
    for (int e = 0; e < 8; e++) probs[n*8 + e] = (float)p[e];
    pair[2*n] = e0; pair[2*n+1] = e1;
    gpair[2*n] = (float)b0; gpair[2*n+1] = (float)b1;
    atomicAdd(&counts[e0], 1);
    atomicAdd(&counts[e1], 1);
  }
}

__global__ void offsets_kernel(const int* __restrict__ counts, int* __restrict__ off,
                               int* __restrict__ cursor) {
  if (threadIdx.x == 0) {
    int a = 0;
    for (int e = 0; e < 8; e++) { off[e] = a; cursor[e] = a; a += counts[e]; }
    off[8] = a;
  }
}

__global__ __launch_bounds__(256) void scatter_kernel(
    const int* __restrict__ pair, const float* __restrict__ gpair, int* __restrict__ cursor,
    int* __restrict__ tok_of_slot, float* __restrict__ gate_of_slot, int* __restrict__ slot_of_tok) {
  int n = blockIdx.x * 256 + threadIdx.x;
  int e0 = pair[2*n], e1 = pair[2*n+1];
  int s0 = atomicAdd(&cursor[e0], 1);
  tok_of_slot[s0] = n; gate_of_slot[s0] = gpair[2*n];   slot_of_tok[2*n] = s0;
  int s1 = atomicAdd(&cursor[e1], 1);
  tok_of_slot[s1] = n; gate_of_slot[s1] = gpair[2*n+1]; slot_of_tok[2*n+1] = s1;
}

__global__ __launch_bounds__(256) void aux_kernel(
    const float* __restrict__ probs, const int* __restrict__ counts, float* __restrict__ outaux) {
  __shared__ double sm[256];
  int t = threadIdx.x;
  int e = t & 7, base = t >> 3;
  double acc = 0.0;
  for (int n = base; n < NTOK; n += 32) acc += (double)probs[n*8 + e];
  sm[t] = acc;
  __syncthreads();
  if (t < 8) {
    double s = 0.0;
    for (int g = 0; g < 32; g++) s += sm[g*8 + t];
    sm[t] = s;
  }
  __syncthreads();
  if (t == 0) {
    double aux = 0.0;
    for (int ee = 0; ee < 8; ee++)
      aux += ((double)counts[ee] * (1.0 / (NTOK*2))) * (sm[ee] * (1.0 / NTOK));
    outaux[0] = (float)(0.08 * aux);   // AUX_COEF * E
  }
}

// ---------------- MoE w1/w3 fused dual-GEMM: A via async global_load_lds DMA ----------------
// R24: A staged by global_load_lds (width 16) into unpadded [128][32] LDS with
// pre-swizzled SOURCE (seg_g = seg_l ^ ((row>>1)&3)) so reads stay 2-way/free.
// Removes A's ds_writes from the wave LDS-issue path (12->10 b128/thread-step)
// and drops LDS 41->36KB (4 blocks/CU cap). W path and barrier structure
// identical to the R17-validated dbuf. Data delivered to MFMA is bit-identical.
__global__ __launch_bounds__(256) void moe13_kernel(
    const short* __restrict__ xn2,
    const float* __restrict__ ew1, const float* __restrict__ eb1,
    const float* __restrict__ ew3, const float* __restrict__ eb3,
    const int* __restrict__ counts, const int* __restrict__ off,
    const int* __restrict__ tok_of_slot, short* __restrict__ hbuf) {
  int e = blockIdx.z;
  int Me = counts[e];
  int m0 = blockIdx.y * 128;
  if (m0 >= Me) return;
  int base = off[e];
  int i0 = blockIdx.x * 64;
  __shared__ __attribute__((aligned(16))) short As[2][128*32];   // unpadded, source-swizzled
  __shared__ __attribute__((aligned(16))) short W1s[2][64*40];
  __shared__ __attribute__((aligned(16))) short W3s[2][64*40];
  int tid = threadIdx.x, lane = tid & 63, wid = tid >> 6;
  int wm = wid >> 1, wn = wid & 1;
  floatx4 zero4 = {0.f,0.f,0.f,0.f};
  floatx4 acc1[4][2], acc3[4][2];
  #pragma unroll
  for (int mi = 0; mi < 4; mi++)
    #pragma unroll
    for (int nj = 0; nj < 2; nj++) { acc1[mi][nj] = zero4; acc3[mi][nj] = zero4; }

  // DMA chunk mapping: chunk c in [0,512) = (row c>>2, seg_l c&3), 16B each, LDS linear at c*16B.
  // Thread t owns chunks t and 256+t; wave w's lanes write [w*64, w*64+64) and +256.
  int arow0 = tid >> 2, arow1 = 64 + (tid >> 2), asl = tid & 3;
  int sg0 = (asl ^ ((arow0 >> 1) & 3)) * 8;   // swizzled global col seg (shorts)
  int sg1 = (asl ^ ((arow1 >> 1) & 3)) * 8;
  int am0 = m0 + arow0, am1 = m0 + arow1;
  const short* Ag0 = xn2 + (size_t)tok_of_slot[base + ((am0 < Me) ? am0 : 0)] * DMODEL + sg0;
  const short* Ag1 = xn2 + (size_t)tok_of_slot[base + ((am1 < Me) ? am1 : 0)] * DMODEL + sg1;

  int wr = tid >> 2, wk = (tid & 3) * 8;
  const float* W1g = ew1 + ((size_t)e*IDIM + i0 + wr)*DMODEL + wk;
  const float* W3g = ew3 + ((size_t)e*IDIM + i0 + wr)*DMODEL + wk;
  int rsel = lane & 15, kseg = (lane >> 4) * 8;

  // prologue: DMA A tile 0 into buffer 0; stage W tile 0
  async_load16(Ag0, &As[0][wid*512]);
  async_load16(Ag1, &As[0][2048 + wid*512]);
  {
    floatx4 u0 = *(const floatx4*)(W1g);
    floatx4 u1 = *(const floatx4*)(W1g + 4);
    floatx4 v0 = *(const floatx4*)(W3g);
    floatx4 v1 = *(const floatx4*)(W3g + 4);
    *(uintx4*)(&W1s[0][wr*40 + wk]) = pack8_bf16(u0, u1);
    *(uintx4*)(&W3s[0][wr*40 + wk]) = pack8_bf16(v0, v1);
  }
  __syncthreads();   // drains vmcnt (DMA complete) + lgkm

  for (int kk = 0; kk < DMODEL; kk += 32) {
    int cur = (kk >> 5) & 1;
    int nxt = cur ^ 1;
    bool more = (kk + 32 < DMODEL);
    // issue next-step A DMA (into nxt: its reads retired at previous barrier)
    // + next W global loads; all latency hides under the MFMA section.
    floatx4 nu0, nu1, nv0, nv1;
    if (more) {
      async_load16(Ag0 + kk + 32, &As[nxt][wid*512]);
      async_load16(Ag1 + kk + 32, &As[nxt][2048 + wid*512]);
      nu0 = *(const floatx4*)(W1g + kk + 32);
      nu1 = *(const floatx4*)(W1g + kk + 36);
      nv0 = *(const floatx4*)(W3g + kk + 32);
      nv1 = *(const floatx4*)(W3g + kk + 36);
    }
    // read cur fragments (A with matching read-side swizzle) + MFMA
    bf16x8 af[4], w1f[2], w3f[2];
    #pragma unroll
    for (int mi = 0; mi < 4; mi++) {
      int arow = wm*64 + mi*16 + rsel;
      int asw = ((kseg >> 3) ^ ((arow >> 1) & 3)) << 3;
      af[mi] = *(const bf16x8*)(&As[cur][arow*32 + asw]);
    }
    #pragma unroll
    for (int nj = 0; nj < 2; nj++) {
      w1f[nj] = *(const bf16x8*)(&W1s[cur][(wn*32 + nj*16 + rsel)*40 + kseg]);
      w3f[nj] = *(const bf16x8*)(&W3s[cur][(wn*32 + nj*16 + rsel)*40 + kseg]);
    }
    #pragma unroll
    for (int mi = 0; mi < 4; mi++)
      #pragma unroll
      for (int nj = 0; nj < 2; nj++) {
        acc1[mi][nj] = __builtin_amdgcn_mfma_f32_16x16x32_bf16(af[mi], w1f[nj], acc1[mi][nj], 0, 0, 0);
        acc3[mi][nj] = __builtin_amdgcn_mfma_f32_16x16x32_bf16(af[mi], w3f[nj], acc3[mi][nj], 0, 0, 0);
      }
    // write W next buffer (disjoint from cur)
    if (more) {
      *(uintx4*)(&W1s[nxt][wr*40 + wk]) = pack8_bf16(nu0, nu1);
      *(uintx4*)(&W3s[nxt][wr*40 + wk]) = pack8_bf16(nv0, nv1);
    }
    __syncthreads();   // waits lgkm + vmcnt(0): DMA into nxt complete before its reads
  }
  int rj = (lane >> 4) * 4, cn = lane & 15;
  #pragma unroll
  for (int mi = 0; mi < 4; mi++) {
    #pragma unroll
    for (int nj = 0; nj < 2; nj++) {
      int i = i0 + wn*32 + nj*16 + cn;
      float be1 = eb1[e*IDIM + i], be3 = eb3[e*IDIM + i];
      #pragma unroll
      for (int j = 0; j < 4; j++) {
        int m = m0 + wm*64 + mi*16 + rj + j;
        if (m < Me) {
          float a = acc1[mi][nj][j] + be1;
          float b = acc3[mi][nj][j] + be3;
          float hval = (a / (1.f + __expf(-a))) * b;
          hbuf[(size_t)(base + m)*IDIM + i] = f2bf(hval);
        }
      }
    }
  }
}

// ---------------- MoE w2 GEMM, SPLIT-K=2, 128x128, double-buffered LDS ----------------
__global__ __launch_bounds__(256) void moe2_kernel(
    const short* __restrict__ hbuf, const float* __restrict__ ew2, const float* __restrict__ eb2,
    const int* __restrict__ counts, const int* __restrict__ off,
    const float* __restrict__ gate_of_slot,
    float* __restrict__ y0, float* __restrict__ y1) {
  int e = blockIdx.z;
  int Me = counts[e];
  int m0 = blockIdx.y * 128;
  if (m0 >= Me) return;
  int base = off[e];
  int n0 = (blockIdx.x & 7) * 128;
  int khalf = blockIdx.x >> 3;
  int kbeg = khalf * (IDIM/2);
  __shared__ __attribute__((aligned(16))) short As[2][128*40];
  __shared__ __attribute__((aligned(16))) short Ws[2][128*40];
  int tid = threadIdx.x, lane = tid & 63, wid = tid >> 6;
  int wm = wid >> 1, wn = wid & 1;
  floatx4 zero4 = {0.f,0.f,0.f,0.f};
  floatx4 acc[4][4];
  #pragma unroll
  for (int mi = 0; mi < 4; mi++)
    #pragma unroll
    for (int nj = 0; nj < 4; nj++) acc[mi][nj] = zero4;

  int ar = tid >> 1, ak = (tid & 1) * 8, kw = (tid & 1) * 16;
  bool aval = (m0 + ar) < Me;
  const short* Ag = hbuf + (size_t)(base + (aval ? (m0 + ar) : 0)) * IDIM + kbeg;
  const float* Wg = ew2 + ((size_t)e*DMODEL + n0 + ar)*IDIM + kbeg;
  int rsel = lane & 15, kseg = (lane >> 4) * 8;

  // prologue: stage tile 0 into buffer 0
  {
    bf16x8 a0 = {0,0,0,0,0,0,0,0}, a1 = {0,0,0,0,0,0,0,0};
    if (aval) {
      a0 = *(const bf16x8*)(Ag + ak);
      a1 = *(const bf16x8*)(Ag + ak + 16);
    }
    floatx4 w0 = *(const floatx4*)(Wg + kw);
    floatx4 w1 = *(const floatx4*)(Wg + kw + 4);
    floatx4 w2 = *(const floatx4*)(Wg + kw + 8);
    floatx4 w3 = *(const floatx4*)(Wg + kw + 12);
    *(bf16x8*)(&As[0][ar*40 + ak])      = a0;
    *(bf16x8*)(&As[0][ar*40 + ak + 16]) = a1;
    *(uintx4*)(&Ws[0][ar*40 + kw])     = pack8_bf16(w0, w1);
    *(uintx4*)(&Ws[0][ar*40 + kw + 8]) = pack8_bf16(w2, w3);
  }
  __syncthreads();

  for (int kk = 0; kk < IDIM/2; kk += 32) {
    int cur = (kk >> 5) & 1;
    int nxt = cur ^ 1;
    bool more = (kk + 32 < IDIM/2);
    bf16x8 na0 = {0,0,0,0,0,0,0,0}, na1 = {0,0,0,0,0,0,0,0};
    floatx4 nw0, nw1, nw2, nw3;
    if (more) {
      if (aval) {
        na0 = *(const bf16x8*)(Ag + kk + 32 + ak);
        na1 = *(const bf16x8*)(Ag + kk + 32 + ak + 16);
      }
      nw0 = *(const floatx4*)(Wg + kk + 32 + kw);
      nw1 = *(const floatx4*)(Wg + kk + 32 + kw + 4);
      nw2 = *(const floatx4*)(Wg + kk + 32 + kw + 8);
      nw3 = *(const floatx4*)(Wg + kk + 32 + kw + 12);
    }
    bf16x8 af[4], wf[4];
    #pragma unroll
    for (int mi = 0; mi < 4; mi++)
      af[mi] = *(const bf16x8*)(&As[cur][(wm*64 + mi*16 + rsel)*40 + kseg]);
    #pragma unroll
    for (int nj = 0; nj < 4; nj++)
      wf[nj] = *(const bf16x8*)(&Ws[cur][(wn*64 + nj*16 + rsel)*40 + kseg]);
    #pragma unroll
    for (int mi = 0; mi < 4; mi++)
      #pragma unroll
      for (int nj = 0; nj < 4; nj++)
        acc[mi][nj] = __builtin_amdgcn_mfma_f32_16x16x32_bf16(af[mi], wf[nj], acc[mi][nj], 0, 0, 0);
    if (more) {
      *(bf16x8*)(&As[nxt][ar*40 + ak])      = na0;
      *(bf16x8*)(&As[nxt][ar*40 + ak + 16]) = na1;
      *(uintx4*)(&Ws[nxt][ar*40 + kw])     = pack8_bf16(nw0, nw1);
      *(uintx4*)(&Ws[nxt][ar*40 + kw + 8]) = pack8_bf16(nw2, nw3);
    }
    __syncthreads();
  }
  int rj = (lane >> 4) * 4, cn = lane & 15;
  float* yout = khalf ? y1 : y0;
  #pragma unroll
  for (int mi = 0; mi < 4; mi++) {
    #pragma unroll
    for (int nj = 0; nj < 4; nj++) {
      int n = n0 + wn*64 + nj*16 + cn;
      float bn = khalf ? 0.f : eb2[e*DMODEL + n];
      #pragma unroll
      for (int j = 0; j < 4; j++) {
        int m = m0 + wm*64 + mi*16 + rj + j;
        if (m < Me) {
          float g = gate_of_slot[base + m];
          yout[(size_t)(base + m)*DMODEL + n] = (acc[mi][nj][j] + bn) * g;
        }
      }
    }
  }
}

// ---------------- combine: out = h1 + (y0+y1)[sA] + (y0+y1)[sB] ----------------
__global__ __launch_bounds__(256) void combine_kernel(
    const float* __restrict__ h1, const float* __restrict__ y0, const float* __restrict__ y1,
    const int* __restrict__ slot_of_tok, float* __restrict__ out) {
  int n = blockIdx.x, t = threadIdx.x;
  int sA = slot_of_tok[2*n], sB = slot_of_tok[2*n+1];
  const floatx4* a   = (const floatx4*)(h1 + (size_t)n*DMODEL);
  const floatx4* y0a = (const floatx4*)(y0 + (size_t)sA*DMODEL);
  const floatx4* y1a = (const floatx4*)(y1 + (size_t)sA*DMODEL);
  const floatx4* y0b = (const floatx4*)(y0 + (size_t)sB*DMODEL);
  const floatx4* y1b = (const floatx4*)(y1 + (size_t)sB*DMODEL);
  floatx4 v = a[t] + (y0a[t] + y1a[t]) + (y0b[t] + y1b[t]);
  ((floatx4*)(out + (size_t)n*DMODEL))[t] = v;
}

extern "C" void kernel_launch(void* const* d_in, const int* in_sizes, int n_in,
                              void* d_out, int out_size, void* d_ws, size_t ws_size,
                              hipStream_t stream) {
  const float* x      = (const float*)d_in[0];
  const float* qkv_w  = (const float*)d_in[1];
  const float* qkv_b  = (const float*)d_in[2];
  const float* out_w  = (const float*)d_in[3];
  const float* out_b  = (const float*)d_in[4];
  const float* ln1_w  = (const float*)d_in[5];
  const float* ln2_w  = (const float*)d_in[6];
  const float* gate_w = (const float*)d_in[7];
  const float* ew1    = (const float*)d_in[8];
  const float* eb1    = (const float*)d_in[9];
  const float* ew2    = (const float*)d_in[10];
  const float* eb2    = (const float*)d_in[11];
  const float* ew3    = (const float*)d_in[12];
  const float* eb3    = (const float*)d_in[13];
  float* out = (float*)d_out;

  // ---- workspace layout (max 84.3 MB; 96.1 MB proven safe) ----
  char* ws = (char*)d_ws;
  float* xn1f   = (float*)(ws + 0);          // 8 MB, live rmsnorm1..qkv
  float* attnof = (float*)(ws + 0);          // 8 MB, live attn..outproj (xn1f dead)
  float* qkvf   = (float*)(ws + 8388608);    // 24 MB, live qkv..vtrans
  float* h1     = (float*)(ws + 8388608);    // 8 MB, live outproj..end (qkvf dead)
  short* xn2    = (short*)(ws + 16777216);   // 4 MB, live rmsnorm2..moe13
  float* yslot1 = (float*)(ws + 16777216);   // 16 MB, live moe2..combine (xn2 dead)
  float* qrf    = (float*)(ws + 33554432);   // 8 MB, live rope..attn
  float* krf    = (float*)(ws + 41943040);   // 8 MB, live rope..attn
  float* vrT    = (float*)(ws + 50331648);   // 8 MB, live vtrans..attn  ([bh][d][t])
  short* hbuf   = (short*)(ws + 33554432);   // 32 MB, live moe13..moe2 (q/k/vT dead)
  float* yslot0 = (float*)(ws + 67108864);   // 16 MB, live moe2..combine
  float* cost         = (float*)(ws + 83886080);  // 128 KB
  float* sint         = (float*)(ws + 84017152);  // 128 KB
  float* probs        = (float*)(ws + 84148224);  //  64 KB
  int*   ctrl         = (int*)  (ws + 84213760);  //   1 KB
  int*   pair         = (int*)  (ws + 84214784);  //  16 KB
  float* gpair        = (float*)(ws + 84231168);  //  16 KB
  int*   slot_of_tok  = (int*)  (ws + 84247552);  //  16 KB
  int*   tok_of_slot  = (int*)  (ws + 84263936);  //  16 KB
  float* gate_of_slot = (float*)(ws + 84280320);  //  16 KB

  int* counts = ctrl;
  int* off    = ctrl + 8;
  int* cursor = ctrl + 20;

  hipMemsetAsync(ctrl, 0, 1024, stream);
  rope_table_kernel<<<T_SEQ, 32, 0, stream>>>(cost, sint);
  rmsnorm_f32_kernel<<<NTOK, 256, 0, stream>>>(x, ln1_w, xn1f);
  gemm_3bf16<0><<<dim3(48, 32), 256, 0, stream>>>(xn1f, qkv_w, qkv_b, nullptr, qkvf, 3072, DMODEL);
  rope_kernel<<<8192, 256, 0, stream>>>(qkvf, cost, sint, qrf, krf);
  vtrans_kernel<<<dim3(32, 16), 256, 0, stream>>>(qkvf, vrT);
  attn_mfma_kernel<<<dim3(32, 16), 256, 0, stream>>>(qrf, krf, vrT, attnof);
  gemm_3bf16<1><<<dim3(16, 32), 256, 0, stream>>>(attnof, out_w, out_b, x, h1, DMODEL, DMODEL);
  rmsnorm_bf16_kernel<<<NTOK, 256, 0, stream>>>(h1, ln2_w, xn2);
  gate_kernel<<<NTOK, 64, 0, stream>>>(h1, ln2_w, gate_w, probs, pair, gpair, counts);
  offsets_kernel<<<1, 64, 0, stream>>>(counts, off, cursor);
  scatter_kernel<<<8, 256, 0, stream>>>(pair, gpair, cursor, tok_of_slot, gate_of_slot, slot_of_tok);
  aux_kernel<<<1, 256, 0, stream>>>(probs, counts, out + 2097152);
  moe13_kernel<<<dim3(64, 16, 8), 256, 0, stream>>>(xn2, ew1, eb1, ew3, eb3, counts, off, tok_of_slot, hbuf);
  moe2_kernel<<<dim3(16, 16, 8), 256, 0, stream>>>(hbuf, ew2, eb2, counts, off, gate_of_slot, yslot0, yslot1);
  combine_kernel<<<NTOK, 256, 0, stream>>>(h1, yslot0, yslot1, slot_of_tok, out);
}

// Round 25
// 532.673 us; speedup vs baseline: 1.0155x; 1.0155x over previous
//
#include <hip/hip_runtime.h>
#include <cstdint>
#include <cstddef>
#include <math.h>

#define T_SEQ  1024
#define DMODEL 1024
#define NHEAD  16
#define HDIM   64
#define NEXP   8
#define IDIM   4096
#define NTOK   2048
#define NSLOT  4096

typedef short bf16x8 __attribute__((ext_vector_type(8)));
typedef short s16x4  __attribute__((ext_vector_type(4)));
typedef float floatx4 __attribute__((ext_vector_type(4)));
typedef unsigned int uintx4 __attribute__((ext_vector_type(4)));

__device__ __forceinline__ float bf2f(short s) {
  return __uint_as_float(((unsigned)(unsigned short)s) << 16);
}
__device__ __forceinline__ short f2bf(float f) {
  unsigned u = __float_as_uint(f);
  unsigned r = (u + 0x7FFFu + ((u >> 16) & 1u)) >> 16;
  return (short)r;
}
// hardware packed fp32->bf16 (RNE), 2 elems / instr; low16 = cvt(arg0)
__device__ __forceinline__ unsigned cvt_pk_bf16(float lo, float hi) {
  unsigned r;
  asm("v_cvt_pk_bf16_f32 %0, %1, %2" : "=v"(r) : "v"(lo), "v"(hi));
  return r;
}
__device__ __forceinline__ uintx4 pack8_bf16(floatx4 a, floatx4 b) {
  uintx4 u;
  u[0] = cvt_pk_bf16(a[0], a[1]);
  u[1] = cvt_pk_bf16(a[2], a[3]);
  u[2] = cvt_pk_bf16(b[0], b[1]);
  u[3] = cvt_pk_bf16(b[2], b[3]);
  return u;
}
// split 8 fp32 into hi-bf16 + lo-bf16 (lo = x - hi, RNE both)
__device__ __forceinline__ void split8(const float* x, uintx4& hi, uintx4& lo) {
  #pragma unroll
  for (int i = 0; i < 4; i++) {
    unsigned h = cvt_pk_bf16(x[2*i], x[2*i+1]);
    hi[i] = h;
    float r0 = x[2*i]   - __uint_as_float(h << 16);
    float r1 = x[2*i+1] - __uint_as_float(h & 0xffff0000u);
    lo[i] = cvt_pk_bf16(r0, r1);
  }
}

// ---------------- RMSNorm: fp32 in -> fp32 out ----------------
__global__ __launch_bounds__(256) void rmsnorm_f32_kernel(
    const float* __restrict__ x, const float* __restrict__ w, float* __restrict__ out) {
  int row = blockIdx.x, tid = threadIdx.x;
  const floatx4* xr = (const floatx4*)(x + (size_t)row * DMODEL);
  floatx4 v = xr[tid];
  float ss = v[0]*v[0] + v[1]*v[1] + v[2]*v[2] + v[3]*v[3];
  #pragma unroll
  for (int off = 32; off > 0; off >>= 1) ss += __shfl_xor(ss, off);
  __shared__ float wsum[4];
  int wid = tid >> 6;
  if ((tid & 63) == 0) wsum[wid] = ss;
  __syncthreads();
  float tot = wsum[0] + wsum[1] + wsum[2] + wsum[3];
  float r = rsqrtf(tot * (1.0f / DMODEL) + 1e-6f);
  floatx4 wv = ((const floatx4*)w)[tid];
  floatx4 o;
  o[0] = v[0]*r*wv[0]; o[1] = v[1]*r*wv[1];
  o[2] = v[2]*r*wv[2]; o[3] = v[3]*r*wv[3];
  ((floatx4*)(out + (size_t)row * DMODEL))[tid] = o;
}

// ---------------- RMSNorm: fp32 in -> bf16 out (for MoE input) ----------------
__global__ __launch_bounds__(256) void rmsnorm_bf16_kernel(
    const float* __restrict__ x, const float* __restrict__ w, short* __restrict__ out) {
  int row = blockIdx.x, tid = threadIdx.x;
  const floatx4* xr = (const floatx4*)(x + (size_t)row * DMODEL);
  floatx4 v = xr[tid];
  float ss = v[0]*v[0] + v[1]*v[1] + v[2]*v[2] + v[3]*v[3];
  #pragma unroll
  for (int off = 32; off > 0; off >>= 1) ss += __shfl_xor(ss, off);
  __shared__ float wsum[4];
  int wid = tid >> 6;
  if ((tid & 63) == 0) wsum[wid] = ss;
  __syncthreads();
  float tot = wsum[0] + wsum[1] + wsum[2] + wsum[3];
  float r = rsqrtf(tot * (1.0f / DMODEL) + 1e-6f);
  floatx4 wv = ((const floatx4*)w)[tid];
  s16x4 o;
  o[0] = f2bf(v[0]*r*wv[0]); o[1] = f2bf(v[1]*r*wv[1]);
  o[2] = f2bf(v[2]*r*wv[2]); o[3] = f2bf(v[3]*r*wv[3]);
  *(s16x4*)(out + (size_t)row * DMODEL + tid*4) = o;
}

// ---------------- split-bf16 MFMA GEMM, double-buffered LDS (R17-validated dbuf) ----------------
// C = A@W^T + bias [+resid]. Issue next-tile loads -> MFMA cur -> split+write nxt
// (disjoint buffer) -> single barrier per K-step.
template<int RESID>
__global__ __launch_bounds__(256) void gemm_3bf16(
    const float* __restrict__ A, const float* __restrict__ W,
    const float* __restrict__ bias, const float* __restrict__ resid,
    float* __restrict__ C, int N, int K) {
  __shared__ __attribute__((aligned(16))) short Ahi[2][64*40];
  __shared__ __attribute__((aligned(16))) short Alo[2][64*40];
  __shared__ __attribute__((aligned(16))) short Whi[2][64*40];
  __shared__ __attribute__((aligned(16))) short Wlo[2][64*40];
  int tid = threadIdx.x, lane = tid & 63, wid = tid >> 6;
  int wm = wid >> 1, wn = wid & 1;
  int m0 = blockIdx.y * 64, n0 = blockIdx.x * 64;
  floatx4 zero4 = {0.f,0.f,0.f,0.f};
  floatx4 acc[2][2];
  #pragma unroll
  for (int mi = 0; mi < 2; mi++)
    #pragma unroll
    for (int nj = 0; nj < 2; nj++) acc[mi][nj] = zero4;

  int ar = tid >> 2, ak = (tid & 3) * 8;
  const float* Ap = A + (size_t)(m0 + ar) * K + ak;
  const float* Wp = W + (size_t)(n0 + ar) * K + ak;
  int rsel = lane & 15, kseg = (lane >> 4) * 8;

  // prologue: stage tile 0 into buffer 0
  {
    float abuf[8], wbuf[8];
    *(floatx4*)(abuf)     = *(const floatx4*)(Ap);
    *(floatx4*)(abuf + 4) = *(const floatx4*)(Ap + 4);
    *(floatx4*)(wbuf)     = *(const floatx4*)(Wp);
    *(floatx4*)(wbuf + 4) = *(const floatx4*)(Wp + 4);
    uintx4 ahi, alo, whi, wlo;
    split8(abuf, ahi, alo);
    split8(wbuf, whi, wlo);
    *(uintx4*)(&Ahi[0][ar*40 + ak]) = ahi;
    *(uintx4*)(&Alo[0][ar*40 + ak]) = alo;
    *(uintx4*)(&Whi[0][ar*40 + ak]) = whi;
    *(uintx4*)(&Wlo[0][ar*40 + ak]) = wlo;
  }
  __syncthreads();

  for (int kk = 0; kk < K; kk += 32) {
    int cur = (kk >> 5) & 1;
    int nxt = cur ^ 1;
    bool more = (kk + 32 < K);
    // issue next-tile global loads (latency hides under MFMAs)
    float nab[8], nwb[8];
    if (more) {
      *(floatx4*)(nab)     = *(const floatx4*)(Ap + kk + 32);
      *(floatx4*)(nab + 4) = *(const floatx4*)(Ap + kk + 36);
      *(floatx4*)(nwb)     = *(const floatx4*)(Wp + kk + 32);
      *(floatx4*)(nwb + 4) = *(const floatx4*)(Wp + kk + 36);
    }
    // read cur fragments + MFMA
    bf16x8 afh[2], afl[2], wfh[2], wfl[2];
    #pragma unroll
    for (int mi = 0; mi < 2; mi++) {
      int row = (wm*32 + mi*16 + rsel)*40 + kseg;
      afh[mi] = *(const bf16x8*)(&Ahi[cur][row]);
      afl[mi] = *(const bf16x8*)(&Alo[cur][row]);
    }
    #pragma unroll
    for (int nj = 0; nj < 2; nj++) {
      int row = (wn*32 + nj*16 + rsel)*40 + kseg;
      wfh[nj] = *(const bf16x8*)(&Whi[cur][row]);
      wfl[nj] = *(const bf16x8*)(&Wlo[cur][row]);
    }
    #pragma unroll
    for (int mi = 0; mi < 2; mi++)
      #pragma unroll
      for (int nj = 0; nj < 2; nj++) {
        acc[mi][nj] = __builtin_amdgcn_mfma_f32_16x16x32_bf16(afl[mi], wfh[nj], acc[mi][nj], 0, 0, 0);
        acc[mi][nj] = __builtin_amdgcn_mfma_f32_16x16x32_bf16(afh[mi], wfl[nj], acc[mi][nj], 0, 0, 0);
        acc[mi][nj] = __builtin_amdgcn_mfma_f32_16x16x32_bf16(afh[mi], wfh[nj], acc[mi][nj], 0, 0, 0);
      }
    // split + write next buffer (disjoint from cur)
    if (more) {
      uintx4 ahi, alo, whi, wlo;
      split8(nab, ahi, alo);
      split8(nwb, whi, wlo);
      *(uintx4*)(&Ahi[nxt][ar*40 + ak]) = ahi;
      *(uintx4*)(&Alo[nxt][ar*40 + ak]) = alo;
      *(uintx4*)(&Whi[nxt][ar*40 + ak]) = whi;
      *(uintx4*)(&Wlo[nxt][ar*40 + ak]) = wlo;
    }
    __syncthreads();
  }
  int rj = (lane >> 4) * 4, cn = lane & 15;
  #pragma unroll
  for (int mi = 0; mi < 2; mi++) {
    #pragma unroll
    for (int nj = 0; nj < 2; nj++) {
      int n = n0 + wn*32 + nj*16 + cn;
      float bn = bias[n];
      #pragma unroll
      for (int j = 0; j < 4; j++) {
        int m = m0 + wm*32 + mi*16 + rj + j;
        float v = acc[mi][nj][j] + bn;
        if (RESID) v += resid[(size_t)m * N + n];
        C[(size_t)m * N + n] = v;
      }
    }
  }
}

// ---------------- RoPE table (fp64 generation) ----------------
__global__ void rope_table_kernel(float* __restrict__ cost, float* __restrict__ sint) {
  int t = blockIdx.x, d = threadIdx.x;  // block 32
  double theta = pow(10000.0, -(double)d / 32.0);
  double f = (double)t * theta;
  cost[t*32 + d] = (float)cos(f);
  sint[t*32 + d] = (float)sin(f);
}

// ---------------- RoPE + transpose q,k to [B][H][T][hd], fp32 ----------------
__global__ __launch_bounds__(256) void rope_kernel(
    const float* __restrict__ qkv, const float* __restrict__ cost, const float* __restrict__ sint,
    float* __restrict__ qr, float* __restrict__ kr) {
  int wid = threadIdx.x >> 6, lane = threadIdx.x & 63;
  int idx = blockIdx.x * 4 + wid;        // over NTOK*NHEAD
  int h = idx & 15, n = idx >> 4;
  int t = n & (T_SEQ - 1), b = n >> 10;
  const float* base = qkv + (size_t)n * 3072 + h * 192;
  int d2 = lane & 31;
  float c = cost[t*32 + d2], s = sint[t*32 + d2];
  float q1 = base[d2],      q2 = base[d2 + 32];
  float k1 = base[64 + d2], k2 = base[96 + d2];
  float qo = (lane < 32) ? (q1*c - q2*s) : (q1*s + q2*c);
  float ko = (lane < 32) ? (k1*c - k2*s) : (k1*s + k2*c);
  size_t orow = ((size_t)(b*NHEAD + h) * T_SEQ + t) * HDIM;
  qr[orow + lane] = qo;
  kr[orow + lane] = ko;
}

// ---------------- V transpose: qkvf -> vrT[bh][d][t]  (for MFMA B-operand) ----------------
__global__ __launch_bounds__(256) void vtrans_kernel(
    const float* __restrict__ qkvf, float* __restrict__ vrT) {
  __shared__ __attribute__((aligned(16))) float tile[64][68];
  int bh = blockIdx.x, t0 = blockIdx.y * 64;
  int b = bh >> 4, h = bh & 15;
  int tid = threadIdx.x;
  int r = tid >> 2, seg = (tid & 3) * 16;
  const float* src = qkvf + ((size_t)(b*T_SEQ + t0 + r))*3072 + h*192 + 128 + seg;
  floatx4 v0 = *(const floatx4*)(src);
  floatx4 v1 = *(const floatx4*)(src + 4);
  floatx4 v2 = *(const floatx4*)(src + 8);
  floatx4 v3 = *(const floatx4*)(src + 12);
  *(floatx4*)(&tile[r][seg])      = v0;
  *(floatx4*)(&tile[r][seg + 4])  = v1;
  *(floatx4*)(&tile[r][seg + 8])  = v2;
  *(floatx4*)(&tile[r][seg + 12]) = v3;
  __syncthreads();
  int dr = r, tseg = seg;
  floatx4 o0, o1, o2, o3;
  #pragma unroll
  for (int i = 0; i < 4; i++) {
    o0[i] = tile[tseg + i][dr];
    o1[i] = tile[tseg + 4 + i][dr];
    o2[i] = tile[tseg + 8 + i][dr];
    o3[i] = tile[tseg + 12 + i][dr];
  }
  float* dst = vrT + ((size_t)(bh*HDIM + dr))*T_SEQ + t0 + tseg;
  *(floatx4*)(dst)      = o0;
  *(floatx4*)(dst + 4)  = o1;
  *(floatx4*)(dst + 8)  = o2;
  *(floatx4*)(dst + 12) = o3;
}

// ---------------- MFMA flash attention, split-bf16 (3-term), fp32-class accuracy ----------------
__global__ __launch_bounds__(256) void attn_mfma_kernel(
    const float* __restrict__ qr_, const float* __restrict__ kr_,
    const float* __restrict__ vrT_, float* __restrict__ attno) {
  __shared__ __attribute__((aligned(16))) short Qhi[64*72];
  __shared__ __attribute__((aligned(16))) short Qlo[64*72];
  __shared__ __attribute__((aligned(16))) short Khi[64*72];
  __shared__ __attribute__((aligned(16))) short Klo[64*72];
  __shared__ __attribute__((aligned(16))) short Vhi[64*72];
  __shared__ __attribute__((aligned(16))) short Vlo[64*72];
  __shared__ __attribute__((aligned(16))) unsigned Pp[64*68];
  int tid = threadIdx.x, lane = tid & 63, w = tid >> 6;
  int bh = blockIdx.x;
  int qt = 15 - (int)blockIdx.y;          // heavy tiles first
  int q0 = qt * 64;
  int b = bh >> 4, h = bh & 15;
  const float* Qb  = qr_  + ((size_t)bh * T_SEQ + q0) * HDIM;
  const float* Kb  = kr_  + (size_t)bh * T_SEQ * HDIM;
  const float* Vtb = vrT_ + (size_t)bh * HDIM * T_SEQ;

  int srow = tid >> 2, sseg = (tid & 3) * 16;
  // stage Q once (split)
  {
    const float* src = Qb + srow*HDIM + sseg;
    float b0[8], b1[8];
    *(floatx4*)(b0)   = *(const floatx4*)(src);
    *(floatx4*)(b0+4) = *(const floatx4*)(src + 4);
    *(floatx4*)(b1)   = *(const floatx4*)(src + 8);
    *(floatx4*)(b1+4) = *(const floatx4*)(src + 12);
    uintx4 h0, l0, h1, l1;
    split8(b0, h0, l0); split8(b1, h1, l1);
    *(uintx4*)(&Qhi[srow*72 + sseg])     = h0;
    *(uintx4*)(&Qhi[srow*72 + sseg + 8]) = h1;
    *(uintx4*)(&Qlo[srow*72 + sseg])     = l0;
    *(uintx4*)(&Qlo[srow*72 + sseg + 8]) = l1;
  }

  int rsel = lane & 15, kseg = (lane >> 4) * 8, cl = lane & 15;
  int rbase = w*16 + (lane >> 4) * 4;   // +j = local q row (C layout)
  const float scale = 0.03125f;          // (D=1024)^-0.5 per reference
  float mrow[4] = {-1e30f,-1e30f,-1e30f,-1e30f};
  float lrow[4] = {0.f,0.f,0.f,0.f};
  floatx4 zero4 = {0.f,0.f,0.f,0.f};
  floatx4 Of[4];
  #pragma unroll
  for (int f = 0; f < 4; f++) Of[f] = zero4;

  int ntiles = qt + 1;
  for (int kt = 0; kt < ntiles; kt++) {
    int kbase = kt << 6;
    const float* kp = Kb  + (size_t)(kbase + srow)*HDIM + sseg;
    const float* vp = Vtb + (size_t)srow*T_SEQ + kbase + sseg;
    float kb0[8], kb1[8], vb0[8], vb1[8];
    *(floatx4*)(kb0)   = *(const floatx4*)(kp);
    *(floatx4*)(kb0+4) = *(const floatx4*)(kp + 4);
    *(floatx4*)(kb1)   = *(const floatx4*)(kp + 8);
    *(floatx4*)(kb1+4) = *(const floatx4*)(kp + 12);
    *(floatx4*)(vb0)   = *(const floatx4*)(vp);
    *(floatx4*)(vb0+4) = *(const floatx4*)(vp + 4);
    *(floatx4*)(vb1)   = *(const floatx4*)(vp + 8);
    *(floatx4*)(vb1+4) = *(const floatx4*)(vp + 12);
    __syncthreads();   // previous tile's reads complete
    {
      uintx4 h0, l0, h1, l1;
      split8(kb0, h0, l0); split8(kb1, h1, l1);
      *(uintx4*)(&Khi[srow*72 + sseg])     = h0;
      *(uintx4*)(&Khi[srow*72 + sseg + 8]) = h1;
      *(uintx4*)(&Klo[srow*72 + sseg])     = l0;
      *(uintx4*)(&Klo[srow*72 + sseg + 8]) = l1;
      split8(vb0, h0, l0); split8(vb1, h1, l1);
      *(uintx4*)(&Vhi[srow*72 + sseg])     = h0;
      *(uintx4*)(&Vhi[srow*72 + sseg + 8]) = h1;
      *(uintx4*)(&Vlo[srow*72 + sseg])     = l0;
      *(uintx4*)(&Vlo[srow*72 + sseg + 8]) = l1;
    }
    __syncthreads();
    // ---- QK^T: S frags (rows w*16.., cols f*16+cl) ----
    floatx4 sf[4];
    #pragma unroll
    for (int f = 0; f < 4; f++) sf[f] = zero4;
    #pragma unroll
    for (int c = 0; c < 2; c++) {
      int ko = c*32 + kseg;
      bf16x8 qh = *(const bf16x8*)(&Qhi[(w*16 + rsel)*72 + ko]);
      bf16x8 ql = *(const bf16x8*)(&Qlo[(w*16 + rsel)*72 + ko]);
      #pragma unroll
      for (int f = 0; f < 4; f++) {
        bf16x8 kh = *(const bf16x8*)(&Khi[(f*16 + rsel)*72 + ko]);
        bf16x8 kl = *(const bf16x8*)(&Klo[(f*16 + rsel)*72 + ko]);
        sf[f] = __builtin_amdgcn_mfma_f32_16x16x32_bf16(ql, kh, sf[f], 0, 0, 0);
        sf[f] = __builtin_amdgcn_mfma_f32_16x16x32_bf16(qh, kl, sf[f], 0, 0, 0);
        sf[f] = __builtin_amdgcn_mfma_f32_16x16x32_bf16(qh, kh, sf[f], 0, 0, 0);
      }
    }
    // ---- causal mask + scale + row max ----
    float pm[4] = {-1e30f,-1e30f,-1e30f,-1e30f};
    #pragma unroll
    for (int f = 0; f < 4; f++) {
      int col = kbase + f*16 + cl;
      #pragma unroll
      for (int j = 0; j < 4; j++) {
        float s = sf[f][j];
        s = (col <= q0 + rbase + j) ? s*scale : -1e30f;
        sf[f][j] = s;
        pm[j] = fmaxf(pm[j], s);
      }
    }
    #pragma unroll
    for (int off = 1; off < 16; off <<= 1)
      #pragma unroll
      for (int j = 0; j < 4; j++) pm[j] = fmaxf(pm[j], __shfl_xor(pm[j], off));
    // ---- online softmax ----
    float sc[4], rs[4] = {0.f,0.f,0.f,0.f};
    #pragma unroll
    for (int j = 0; j < 4; j++) {
      float mn = fmaxf(mrow[j], pm[j]);
      sc[j] = __expf(mrow[j] - mn);
      mrow[j] = mn;
    }
    #pragma unroll
    for (int f = 0; f < 4; f++) {
      #pragma unroll
      for (int j = 0; j < 4; j++) {
        float p = (sf[f][j] > -1e29f) ? __expf(sf[f][j] - mrow[j]) : 0.f;
        rs[j] += p;
        unsigned hp = cvt_pk_bf16(p, 0.f);
        float ph = __uint_as_float(hp << 16);
        unsigned lp = cvt_pk_bf16(p - ph, 0.f);
        Pp[(rbase + j)*68 + f*16 + cl] = (hp << 16) | (lp & 0xffffu);
      }
    }
    #pragma unroll
    for (int off = 1; off < 16; off <<= 1)
      #pragma unroll
      for (int j = 0; j < 4; j++) rs[j] += __shfl_xor(rs[j], off);
    #pragma unroll
    for (int j = 0; j < 4; j++) lrow[j] = lrow[j]*sc[j] + rs[j];
    #pragma unroll
    for (int f = 0; f < 4; f++)
      #pragma unroll
      for (int j = 0; j < 4; j++) Of[f][j] *= sc[j];
    __syncthreads();   // P visible (ordering safety)
    // ---- PV: O += P * V^T^T  (A=P rows q, B=VT rows d) ----
    #pragma unroll
    for (int c = 0; c < 2; c++) {
      int prow = (w*16 + rsel)*68 + c*32 + kseg;
      uintx4 d0 = *(const uintx4*)(&Pp[prow]);
      uintx4 d1 = *(const uintx4*)(&Pp[prow + 4]);
      uintx4 phw, plw;
      phw[0] = (d0[0] >> 16) | (d0[1] & 0xffff0000u);
      phw[1] = (d0[2] >> 16) | (d0[3] & 0xffff0000u);
      phw[2] = (d1[0] >> 16) | (d1[1] & 0xffff0000u);
      phw[3] = (d1[2] >> 16) | (d1[3] & 0xffff0000u);
      plw[0] = (d0[0] & 0xffffu) | (d0[1] << 16);
      plw[1] = (d0[2] & 0xffffu) | (d0[3] << 16);
      plw[2] = (d1[0] & 0xffffu) | (d1[1] << 16);
      plw[3] = (d1[2] & 0xffffu) | (d1[3] << 16);
      bf16x8 Ph = *(bf16x8*)&phw;
      bf16x8 Pl = *(bf16x8*)&plw;
      int ko = c*32 + kseg;
      #pragma unroll
      for (int f = 0; f < 4; f++) {
        bf16x8 vh = *(const bf16x8*)(&Vhi[(f*16 + rsel)*72 + ko]);
        bf16x8 vl = *(const bf16x8*)(&Vlo[(f*16 + rsel)*72 + ko]);
        Of[f] = __builtin_amdgcn_mfma_f32_16x16x32_bf16(Pl, vh, Of[f], 0, 0, 0);
        Of[f] = __builtin_amdgcn_mfma_f32_16x16x32_bf16(Ph, vl, Of[f], 0, 0, 0);
        Of[f] = __builtin_amdgcn_mfma_f32_16x16x32_bf16(Ph, vh, Of[f], 0, 0, 0);
      }
    }
  }
  // ---- epilogue ----
  #pragma unroll
  for (int j = 0; j < 4; j++) {
    float inv = 1.0f / lrow[j];
    size_t rowoff = ((size_t)(b*T_SEQ + q0 + rbase + j))*DMODEL + h*HDIM;
    #pragma unroll
    for (int f = 0; f < 4; f++)
      attno[rowoff + f*16 + cl] = Of[f][j] * inv;
  }
}

// ---------------- gate: FULL FP64 path (inline rmsnorm of fp32-accurate h1) ----------------
__global__ __launch_bounds__(64) void gate_kernel(
    const float* __restrict__ h1, const float* __restrict__ lnw, const float* __restrict__ gw,
    float* __restrict__ probs, int* __restrict__ pair, float* __restrict__ gpair,
    int* __restrict__ counts) {
  int n = blockIdx.x, lane = threadIdx.x;
  const float* xp = h1 + (size_t)n * DMODEL + lane*16;
  float xv[16];
  double ss = 0.0;
  #pragma unroll
  for (int j = 0; j < 16; j++) { xv[j] = xp[j]; ss += (double)xv[j] * (double)xv[j]; }
  #pragma unroll
  for (int off = 32; off > 0; off >>= 1) ss += __shfl_xor(ss, off);
  double r = 1.0 / sqrt(ss * (1.0 / DMODEL) + 1e-6);
  const float* wp = lnw + lane*16;
  double xf[16];
  #pragma unroll
  for (int j = 0; j < 16; j++) xf[j] = (double)xv[j] * r * (double)wp[j];
  double logit[8];
  #pragma unroll
  for (int e = 0; e < 8; e++) {
    const float* g = gw + e*DMODEL + lane*16;
    double acc = 0.0;
    #pragma unroll
    for (int j = 0; j < 16; j++) acc += xf[j] * (double)g[j];
    logit[e] = acc;
  }
  #pragma unroll
  for (int e = 0; e < 8; e++)
    #pragma unroll
    for (int off = 32; off > 0; off >>= 1) logit[e] += __shfl_xor(logit[e], off);
  double mxl = logit[0];
  #pragma unroll
  for (int e = 1; e < 8; e++) mxl = fmax(mxl, logit[e]);
  double p[8], Z = 0.0;
  #pragma unroll
  for (int e = 0; e < 8; e++) { p[e] = exp(logit[e] - mxl); Z += p[e]; }
  double invZ = 1.0 / Z;
  #pragma unroll
  for (int e = 0; e < 8; e++) p[e] *= invZ;
  int e0 = 0; double b0 = p[0];
  #pragma unroll
  for (int e = 1; e < 8; e++) if (p[e] > b0) { b0 = p[e]; e0 = e; }
  int e1 = -1; double b1 = -1.0;
  #pragma unroll
  for (int e = 0; e < 8; e++) if (e != e0 && p[e] > b1) { b1 = p[e]; e1 = e; }
  if (lane == 0) {
    #pragma unroll
    for (int e = 0; e < 8; e++) probs[n*8 + e] = (float)p[e];
    pair[2*n] = e0; pair[2*n+1] = e1;
    gpair[2*n] = (float)b0; gpair[2*n+1] = (float)b1;
    atomicAdd(&counts[e0], 1);
    atomicAdd(&counts[e1], 1);
  }
}

__global__ void offsets_kernel(const int* __restrict__ counts, int* __restrict__ off,
                               int* __restrict__ cursor) {
  if (threadIdx.x == 0) {
    int a = 0;
    for (int e = 0; e < 8; e++) { off[e] = a; cursor[e] = a; a += counts[e]; }
    off[8] = a;
  }
}

__global__ __launch_bounds__(256) void scatter_kernel(
    const int* __restrict__ pair, const float* __restrict__ gpair, int* __restrict__ cursor,
    int* __restrict__ tok_of_slot, float* __restrict__ gate_of_slot, int* __restrict__ slot_of_tok) {
  int n = blockIdx.x * 256 + threadIdx.x;
  int e0 = pair[2*n], e1 = pair[2*n+1];
  int s0 = atomicAdd(&cursor[e0], 1);
  tok_of_slot[s0] = n; gate_of_slot[s0] = gpair[2*n];   slot_of_tok[2*n] = s0;
  int s1 = atomicAdd(&cursor[e1], 1);
  tok_of_slot[s1] = n; gate_of_slot[s1] = gpair[2*n+1]; slot_of_tok[2*n+1] = s1;
}

__global__ __launch_bounds__(256) void aux_kernel(
    const float* __restrict__ probs, const int* __restrict__ counts, float* __restrict__ outaux) {
  __shared__ double sm[256];
  int t = threadIdx.x;
  int e = t & 7, base = t >> 3;
  double acc = 0.0;
  for (int n = base; n < NTOK; n += 32) acc += (double)probs[n*8 + e];
  sm[t] = acc;
  __syncthreads();
  if (t < 8) {
    double s = 0.0;
    for (int g = 0; g < 32; g++) s += sm[g*8 + t];
    sm[t] = s;
  }
  __syncthreads();
  if (t == 0) {
    double aux = 0.0;
    for (int ee = 0; ee < 8; ee++)
      aux += ((double)counts[ee] * (1.0 / (NTOK*2))) * (sm[ee] * (1.0 / NTOK));
    outaux[0] = (float)(0.08 * aux);   // AUX_COEF * E
  }
}

// ---------------- MoE w1/w3 fused dual-GEMM: double-buffered LDS, 1 barrier/K-step ----------------
// Final form. Session evidence: reg-staged dbuf (this), DMA-A (R24), W-reg-direct (R22),
// and all tile variants land at MfmaUtil 17-18% — the K-step serial chain is the
// structural limit of the 2-barrier schedule; escape requires the 8-phase rewrite.
__global__ __launch_bounds__(256) void moe13_kernel(
    const short* __restrict__ xn2,
    const float* __restrict__ ew1, const float* __restrict__ eb1,
    const float* __restrict__ ew3, const float* __restrict__ eb3,
    const int* __restrict__ counts, const int* __restrict__ off,
    const int* __restrict__ tok_of_slot, short* __restrict__ hbuf) {
  int e = blockIdx.z;
  int Me = counts[e];
  int m0 = blockIdx.y * 128;
  if (m0 >= Me) return;
  int base = off[e];
  int i0 = blockIdx.x * 64;
  __shared__ __attribute__((aligned(16))) short As[2][128*40];
  __shared__ __attribute__((aligned(16))) short W1s[2][64*40];
  __shared__ __attribute__((aligned(16))) short W3s[2][64*40];
  int tid = threadIdx.x, lane = tid & 63, wid = tid >> 6;
  int wm = wid >> 1, wn = wid & 1;
  floatx4 zero4 = {0.f,0.f,0.f,0.f};
  floatx4 acc1[4][2], acc3[4][2];
  #pragma unroll
  for (int mi = 0; mi < 4; mi++)
    #pragma unroll
    for (int nj = 0; nj < 2; nj++) { acc1[mi][nj] = zero4; acc3[mi][nj] = zero4; }

  int ar = tid >> 1, ak = (tid & 1) * 8;
  int am = m0 + ar;
  bool aval = (am < Me);
  const short* Ag = xn2 + (size_t)(aval ? tok_of_slot[base + am] : 0) * DMODEL;
  int wr = tid >> 2, wk = (tid & 3) * 8;
  const float* W1g = ew1 + ((size_t)e*IDIM + i0 + wr)*DMODEL + wk;
  const float* W3g = ew3 + ((size_t)e*IDIM + i0 + wr)*DMODEL + wk;
  int rsel = lane & 15, kseg = (lane >> 4) * 8;

  // prologue: stage tile 0 into buffer 0
  {
    bf16x8 a0 = {0,0,0,0,0,0,0,0}, a1 = {0,0,0,0,0,0,0,0};
    if (aval) {
      a0 = *(const bf16x8*)(Ag + ak);
      a1 = *(const bf16x8*)(Ag + ak + 16);
    }
    floatx4 u0 = *(const floatx4*)(W1g);
    floatx4 u1 = *(const floatx4*)(W1g + 4);
    floatx4 v0 = *(const floatx4*)(W3g);
    floatx4 v1 = *(const floatx4*)(W3g + 4);
    *(bf16x8*)(&As[0][ar*40 + ak])      = a0;
    *(bf16x8*)(&As[0][ar*40 + ak + 16]) = a1;
    *(uintx4*)(&W1s[0][wr*40 + wk]) = pack8_bf16(u0, u1);
    *(uintx4*)(&W3s[0][wr*40 + wk]) = pack8_bf16(v0, v1);
  }
  __syncthreads();

  for (int kk = 0; kk < DMODEL; kk += 32) {
    int cur = (kk >> 5) & 1;
    int nxt = cur ^ 1;
    bool more = (kk + 32 < DMODEL);
    bf16x8 na0 = {0,0,0,0,0,0,0,0}, na1 = {0,0,0,0,0,0,0,0};
    floatx4 nu0, nu1, nv0, nv1;
    if (more) {
      if (aval) {
        na0 = *(const bf16x8*)(Ag + kk + 32 + ak);
        na1 = *(const bf16x8*)(Ag + kk + 32 + ak + 16);
      }
      nu0 = *(const floatx4*)(W1g + kk + 32);
      nu1 = *(const floatx4*)(W1g + kk + 36);
      nv0 = *(const floatx4*)(W3g + kk + 32);
      nv1 = *(const floatx4*)(W3g + kk + 36);
    }
    bf16x8 af[4], w1f[2], w3f[2];
    #pragma unroll
    for (int mi = 0; mi < 4; mi++)
      af[mi] = *(const bf16x8*)(&As[cur][(wm*64 + mi*16 + rsel)*40 + kseg]);
    #pragma unroll
    for (int nj = 0; nj < 2; nj++) {
      w1f[nj] = *(const bf16x8*)(&W1s[cur][(wn*32 + nj*16 + rsel)*40 + kseg]);
      w3f[nj] = *(const bf16x8*)(&W3s[cur][(wn*32 + nj*16 + rsel)*40 + kseg]);
    }
    #pragma unroll
    for (int mi = 0; mi < 4; mi++)
      #pragma unroll
      for (int nj = 0; nj < 2; nj++) {
        acc1[mi][nj] = __builtin_amdgcn_mfma_f32_16x16x32_bf16(af[mi], w1f[nj], acc1[mi][nj], 0, 0, 0);
        acc3[mi][nj] = __builtin_amdgcn_mfma_f32_16x16x32_bf16(af[mi], w3f[nj], acc3[mi][nj], 0, 0, 0);
      }
    if (more) {
      *(bf16x8*)(&As[nxt][ar*40 + ak])      = na0;
      *(bf16x8*)(&As[nxt][ar*40 + ak + 16]) = na1;
      *(uintx4*)(&W1s[nxt][wr*40 + wk]) = pack8_bf16(nu0, nu1);
      *(uintx4*)(&W3s[nxt][wr*40 + wk]) = pack8_bf16(nv0, nv1);
    }
    __syncthreads();
  }
  int rj = (lane >> 4) * 4, cn = lane & 15;
  #pragma unroll
  for (int mi = 0; mi < 4; mi++) {
    #pragma unroll
    for (int nj = 0; nj < 2; nj++) {
      int i = i0 + wn*32 + nj*16 + cn;
      float be1 = eb1[e*IDIM + i], be3 = eb3[e*IDIM + i];
      #pragma unroll
      for (int j = 0; j < 4; j++) {
        int m = m0 + wm*64 + mi*16 + rj + j;
        if (m < Me) {
          float a = acc1[mi][nj][j] + be1;
          float b = acc3[mi][nj][j] + be3;
          float hval = (a / (1.f + __expf(-a))) * b;
          hbuf[(size_t)(base + m)*IDIM + i] = f2bf(hval);
        }
      }
    }
  }
}

// ---------------- MoE w2 GEMM, SPLIT-K=2, 128x128, double-buffered LDS ----------------
__global__ __launch_bounds__(256) void moe2_kernel(
    const short* __restrict__ hbuf, const float* __restrict__ ew2, const float* __restrict__ eb2,
    const int* __restrict__ counts, const int* __restrict__ off,
    const float* __restrict__ gate_of_slot,
    float* __restrict__ y0, float* __restrict__ y1) {
  int e = blockIdx.z;
  int Me = counts[e];
  int m0 = blockIdx.y * 128;
  if (m0 >= Me) return;
  int base = off[e];
  int n0 = (blockIdx.x & 7) * 128;
  int khalf = blockIdx.x >> 3;
  int kbeg = khalf * (IDIM/2);
  __shared__ __attribute__((aligned(16))) short As[2][128*40];
  __shared__ __attribute__((aligned(16))) short Ws[2][128*40];
  int tid = threadIdx.x, lane = tid & 63, wid = tid >> 6;
  int wm = wid >> 1, wn = wid & 1;
  floatx4 zero4 = {0.f,0.f,0.f,0.f};
  floatx4 acc[4][4];
  #pragma unroll
  for (int mi = 0; mi < 4; mi++)
    #pragma unroll
    for (int nj = 0; nj < 4; nj++) acc[mi][nj] = zero4;

  int ar = tid >> 1, ak = (tid & 1) * 8, kw = (tid & 1) * 16;
  bool aval = (m0 + ar) < Me;
  const short* Ag = hbuf + (size_t)(base + (aval ? (m0 + ar) : 0)) * IDIM + kbeg;
  const float* Wg = ew2 + ((size_t)e*DMODEL + n0 + ar)*IDIM + kbeg;
  int rsel = lane & 15, kseg = (lane >> 4) * 8;

  // prologue: stage tile 0 into buffer 0
  {
    bf16x8 a0 = {0,0,0,0,0,0,0,0}, a1 = {0,0,0,0,0,0,0,0};
    if (aval) {
      a0 = *(const bf16x8*)(Ag + ak);
      a1 = *(const bf16x8*)(Ag + ak + 16);
    }
    floatx4 w0 = *(const floatx4*)(Wg + kw);
    floatx4 w1 = *(const floatx4*)(Wg + kw + 4);
    floatx4 w2 = *(const floatx4*)(Wg + kw + 8);
    floatx4 w3 = *(const floatx4*)(Wg + kw + 12);
    *(bf16x8*)(&As[0][ar*40 + ak])      = a0;
    *(bf16x8*)(&As[0][ar*40 + ak + 16]) = a1;
    *(uintx4*)(&Ws[0][ar*40 + kw])     = pack8_bf16(w0, w1);
    *(uintx4*)(&Ws[0][ar*40 + kw + 8]) = pack8_bf16(w2, w3);
  }
  __syncthreads();

  for (int kk = 0; kk < IDIM/2; kk += 32) {
    int cur = (kk >> 5) & 1;
    int nxt = cur ^ 1;
    bool more = (kk + 32 < IDIM/2);
    bf16x8 na0 = {0,0,0,0,0,0,0,0}, na1 = {0,0,0,0,0,0,0,0};
    floatx4 nw0, nw1, nw2, nw3;
    if (more) {
      if (aval) {
        na0 = *(const bf16x8*)(Ag + kk + 32 + ak);
        na1 = *(const bf16x8*)(Ag + kk + 32 + ak + 16);
      }
      nw0 = *(const floatx4*)(Wg + kk + 32 + kw);
      nw1 = *(const floatx4*)(Wg + kk + 32 + kw + 4);
      nw2 = *(const floatx4*)(Wg + kk + 32 + kw + 8);
      nw3 = *(const floatx4*)(Wg + kk + 32 + kw + 12);
    }
    bf16x8 af[4], wf[4];
    #pragma unroll
    for (int mi = 0; mi < 4; mi++)
      af[mi] = *(const bf16x8*)(&As[cur][(wm*64 + mi*16 + rsel)*40 + kseg]);
    #pragma unroll
    for (int nj = 0; nj < 4; nj++)
      wf[nj] = *(const bf16x8*)(&Ws[cur][(wn*64 + nj*16 + rsel)*40 + kseg]);
    #pragma unroll
    for (int mi = 0; mi < 4; mi++)
      #pragma unroll
      for (int nj = 0; nj < 4; nj++)
        acc[mi][nj] = __builtin_amdgcn_mfma_f32_16x16x32_bf16(af[mi], wf[nj], acc[mi][nj], 0, 0, 0);
    if (more) {
      *(bf16x8*)(&As[nxt][ar*40 + ak])      = na0;
      *(bf16x8*)(&As[nxt][ar*40 + ak + 16]) = na1;
      *(uintx4*)(&Ws[nxt][ar*40 + kw])     = pack8_bf16(nw0, nw1);
      *(uintx4*)(&Ws[nxt][ar*40 + kw + 8]) = pack8_bf16(nw2, nw3);
    }
    __syncthreads();
  }
  int rj = (lane >> 4) * 4, cn = lane & 15;
  float* yout = khalf ? y1 : y0;
  #pragma unroll
  for (int mi = 0; mi < 4; mi++) {
    #pragma unroll
    for (int nj = 0; nj < 4; nj++) {
      int n = n0 + wn*64 + nj*16 + cn;
      float bn = khalf ? 0.f : eb2[e*DMODEL + n];
      #pragma unroll
      for (int j = 0; j < 4; j++) {
        int m = m0 + wm*64 + mi*16 + rj + j;
        if (m < Me) {
          float g = gate_of_slot[base + m];
          yout[(size_t)(base + m)*DMODEL + n] = (acc[mi][nj][j] + bn) * g;
        }
      }
    }
  }
}

// ---------------- combine: out = h1 + (y0+y1)[sA] + (y0+y1)[sB] ----------------
__global__ __launch_bounds__(256) void combine_kernel(
    const float* __restrict__ h1, const float* __restrict__ y0, const float* __restrict__ y1,
    const int* __restrict__ slot_of_tok, float* __restrict__ out) {
  int n = blockIdx.x, t = threadIdx.x;
  int sA = slot_of_tok[2*n], sB = slot_of_tok[2*n+1];
  const floatx4* a   = (const floatx4*)(h1 + (size_t)n*DMODEL);
  const floatx4* y0a = (const floatx4*)(y0 + (size_t)sA*DMODEL);
  const floatx4* y1a = (const floatx4*)(y1 + (size_t)sA*DMODEL);
  const floatx4* y0b = (const floatx4*)(y0 + (size_t)sB*DMODEL);
  const floatx4* y1b = (const floatx4*)(y1 + (size_t)sB*DMODEL);
  floatx4 v = a[t] + (y0a[t] + y1a[t]) + (y0b[t] + y1b[t]);
  ((floatx4*)(out + (size_t)n*DMODEL))[t] = v;
}

extern "C" void kernel_launch(void* const* d_in, const int* in_sizes, int n_in,
                              void* d_out, int out_size, void* d_ws, size_t ws_size,
                              hipStream_t stream) {
  const float* x      = (const float*)d_in[0];
  const float* qkv_w  = (const float*)d_in[1];
  const float* qkv_b  = (const float*)d_in[2];
  const float* out_w  = (const float*)d_in[3];
  const float* out_b  = (const float*)d_in[4];
  const float* ln1_w  = (const float*)d_in[5];
  const float* ln2_w  = (const float*)d_in[6];
  const float* gate_w = (const float*)d_in[7];
  const float* ew1    = (const float*)d_in[8];
  const float* eb1    = (const float*)d_in[9];
  const float* ew2    = (const float*)d_in[10];
  const float* eb2    = (const float*)d_in[11];
  const float* ew3    = (const float*)d_in[12];
  const float* eb3    = (const float*)d_in[13];
  float* out = (float*)d_out;

  // ---- workspace layout (max 84.3 MB; 96.1 MB proven safe) ----
  char* ws = (char*)d_ws;
  float* xn1f   = (float*)(ws + 0);          // 8 MB, live rmsnorm1..qkv
  float* attnof = (float*)(ws + 0);          // 8 MB, live attn..outproj (xn1f dead)
  float* qkvf   = (float*)(ws + 8388608);    // 24 MB, live qkv..vtrans
  float* h1     = (float*)(ws + 8388608);    // 8 MB, live outproj..end (qkvf dead)
  short* xn2    = (short*)(ws + 16777216);   // 4 MB, live rmsnorm2..moe13
  float* yslot1 = (float*)(ws + 16777216);   // 16 MB, live moe2..combine (xn2 dead)
  float* qrf    = (float*)(ws + 33554432);   // 8 MB, live rope..attn
  float* krf    = (float*)(ws + 41943040);   // 8 MB, live rope..attn
  float* vrT    = (float*)(ws + 50331648);   // 8 MB, live vtrans..attn  ([bh][d][t])
  short* hbuf   = (short*)(ws + 33554432);   // 32 MB, live moe13..moe2 (q/k/vT dead)
  float* yslot0 = (float*)(ws + 67108864);   // 16 MB, live moe2..combine
  float* cost         = (float*)(ws + 83886080);  // 128 KB
  float* sint         = (float*)(ws + 84017152);  // 128 KB
  float* probs        = (float*)(ws + 84148224);  //  64 KB
  int*   ctrl         = (int*)  (ws + 84213760);  //   1 KB
  int*   pair         = (int*)  (ws + 84214784);  //  16 KB
  float* gpair        = (float*)(ws + 84231168);  //  16 KB
  int*   slot_of_tok  = (int*)  (ws + 84247552);  //  16 KB
  int*   tok_of_slot  = (int*)  (ws + 84263936);  //  16 KB
  float* gate_of_slot = (float*)(ws + 84280320);  //  16 KB

  int* counts = ctrl;
  int* off    = ctrl + 8;
  int* cursor = ctrl + 20;

  hipMemsetAsync(ctrl, 0, 1024, stream);
  rope_table_kernel<<<T_SEQ, 32, 0, stream>>>(cost, sint);
  rmsnorm_f32_kernel<<<NTOK, 256, 0, stream>>>(x, ln1_w, xn1f);
  gemm_3bf16<0><<<dim3(48, 32), 256, 0, stream>>>(xn1f, qkv_w, qkv_b, nullptr, qkvf, 3072, DMODEL);
  rope_kernel<<<8192, 256, 0, stream>>>(qkvf, cost, sint, qrf, krf);
  vtrans_kernel<<<dim3(32, 16), 256, 0, stream>>>(qkvf, vrT);
  attn_mfma_kernel<<<dim3(32, 16), 256, 0, stream>>>(qrf, krf, vrT, attnof);
  gemm_3bf16<1><<<dim3(16, 32), 256, 0, stream>>>(attnof, out_w, out_b, x, h1, DMODEL, DMODEL);
  rmsnorm_bf16_kernel<<<NTOK, 256, 0, stream>>>(h1, ln2_w, xn2);
  gate_kernel<<<NTOK, 64, 0, stream>>>(h1, ln2_w, gate_w, probs, pair, gpair, counts);
  offsets_kernel<<<1, 64, 0, stream>>>(counts, off, cursor);
  scatter_kernel<<<8, 256, 0, stream>>>(pair, gpair, cursor, tok_of_slot, gate_of_slot, slot_of_tok);
  aux_kernel<<<1, 256, 0, stream>>>(probs, counts, out + 2097152);
  moe13_kernel<<<dim3(64, 16, 8), 256, 0, stream>>>(xn2, ew1, eb1, ew3, eb3, counts, off, tok_of_slot, hbuf);
  moe2_kernel<<<dim3(16, 16, 8), 256, 0, stream>>>(hbuf, ew2, eb2, counts, off, gate_of_slot, yslot0, yslot1);
  combine_kernel<<<NTOK, 256, 0, stream>>>(h1, yslot0, yslot1, slot_of_tok, out);
}